// Round 12
// baseline (92.343 us; speedup 1.0000x reference)
//
#include <hip/hip_runtime.h>

typedef __attribute__((ext_vector_type(8))) short bf16x8;
typedef __attribute__((ext_vector_type(4))) float f32x4;

namespace {

constexpr int B = 32, T = 128, V = 128, F = 64, O = 64;
constexpr int TPB = 16;   // t-tiles per block; grid = (8, 32) = 256 blocks = 1/CU

// ws layout (bytes):
//   [acat_f bf16: B * (8 ks * 8 r2 * 64 lane) frags * 16B = 2 MiB]   fragment-major Acat
//   [tht_f  bf16: (2 ks * 12 nf * 64 lane) frags * 16B = 24 KiB]     fragment-major ThT
//   [ldg    f32 : B*V = 16 KiB]
constexpr size_t WS_THT_OFF = (size_t)B * 64 * 64 * 8 * 2;   // 2 MiB
constexpr size_t WS_LDG_OFF = WS_THT_OFF + 1536 * 8 * 2;     // +24 KiB

__device__ inline unsigned short f2bf(float f) {
    unsigned u = __builtin_bit_cast(unsigned, f);
    u += 0x7FFFu + ((u >> 16) & 1u);
    return (unsigned short)(u >> 16);
}

// ---------------- prep: fragment-major Acat/ThT, ldiag (unchanged) ----------------
__global__ __launch_bounds__(256) void prep(const float* __restrict__ W,
                                            const float* __restrict__ Theta,
                                            unsigned short* __restrict__ acat_f,
                                            unsigned short* __restrict__ tht_f,
                                            float* __restrict__ ldg) {
    const int tid = threadIdx.x;
    if (blockIdx.x == B) {
        for (int i = 0; i < 6; ++i) {
            int fi = tid + i * 256;                 // [0,1536)
            int ks = fi / 768, rem = fi % 768;
            int nf = rem >> 6, lane = rem & 63;
            int n = nf * 16 + (lane & 15);
            int f0 = ks * 32 + (lane >> 4) * 8;
            unsigned short vals[8];
#pragma unroll
            for (int j = 0; j < 8; ++j) {
                int f = f0 + j;
                float v;
                if (n < 64)       v = Theta[f * 64 + n] - Theta[2 * 4096 + f * 64 + n];
                else if (n < 128) v = Theta[4096 + f * 64 + (n - 64)];
                else              v = Theta[2 * 4096 + f * 64 + (n - 128)];
                vals[j] = f2bf(v);
            }
            *(bf16x8*)(tht_f + (size_t)fi * 8) = *(bf16x8*)vals;
        }
        return;
    }
    const int b = blockIdx.x;
    const float* Wb = W + (size_t)b * V * V;
    __shared__ float Wl[V][V + 1];
    for (int i = 0; i < V * V / 256; ++i) {
        int idx = tid + i * 256;
        Wl[idx >> 7][idx & 127] = Wb[idx];
    }
    __syncthreads();
    if (tid < V) {
        float s = 0.f;
        for (int i = 0; i < V; ++i) s += Wl[i][tid];       // deg[u] = sum_i W[i][u]
        ldg[b * V + tid] = s - 1.0f - Wl[tid][tid];        // ldiag
    }
    unsigned short* ab_f = acat_f + (size_t)b * 32768;
    for (int i = 0; i < 16; ++i) {
        int fi = tid + i * 256;                    // [0,4096)
        int ks = fi >> 9, rem = fi & 511;
        int r2 = rem >> 6, lane = rem & 63;
        int u = r2 * 16 + (lane & 15);
        int kv0 = ks * 32 + (lane >> 4) * 8;
        unsigned short vals[8];
#pragma unroll
        for (int j = 0; j < 8; ++j) {
            int kv = kv0 + j, v = kv & 127;
            float wv = Wl[v][u];
            float val = (v == u) ? 0.f : ((kv < 128) ? -wv : 2.f * wv * wv);
            vals[j] = f2bf(val);
        }
        *(bf16x8*)(ab_f + (size_t)fi * 8) = *(bf16x8*)vals;
    }
}

// ---------------- main: 2-D wave split (uq x oh); ThT+Acat+ldiag all in registers ----------------
__global__ __launch_bounds__(512, 1) void graph_conv_main(
    const float* __restrict__ x, const unsigned short* __restrict__ acat_f,
    const unsigned short* __restrict__ tht_f, const float* __restrict__ ldg,
    float* __restrict__ out) {
    const int t0 = blockIdx.x * TPB, b = blockIdx.y;
    const int tid = threadIdx.x;                 // 0..511
    const int lane = tid & 63, w = tid >> 6;
    const int uq = w & 3;                        // u/v-slab [32uq, 32uq+32)
    const int oh = w >> 2;                       // o-half  [32oh, 32oh+32)
    const int lr = lane & 15, lg = lane >> 4;

    __shared__ __align__(16) float xbuf[2][V * F];          // 64 KB fp32, src-side swizzle
    __shared__ __align__(16) unsigned short zc1[8192];      // 16 KB [o=64][v=128]
    __shared__ __align__(16) unsigned short zc2[8192];      // 16 KB
    // total 96 KB -> 1 block/CU

    const float* xb = x + ((size_t)(b * T + t0)) * (V * F);

    // ---- hoisted register operands (all t-invariant) ----
    bf16x8 af_r[2][8];   // Acat[u-slab][256kv]
#pragma unroll
    for (int ks = 0; ks < 8; ++ks)
#pragma unroll
        for (int uf = 0; uf < 2; ++uf)
            af_r[uf][ks] = *(const bf16x8*)(acat_f +
                (((size_t)b * 64 + ks * 8 + 2 * uq + uf) * 64 + lane) * 8);

    bf16x8 th_r[3][2][2];   // [mat][nf16 within o-half][kf]
#pragma unroll
    for (int m = 0; m < 3; ++m)
#pragma unroll
        for (int i = 0; i < 2; ++i)
#pragma unroll
            for (int kf = 0; kf < 2; ++kf) {
                int nf = m * 4 + 2 * oh + i;
                th_r[m][i][kf] = *(const bf16x8*)(tht_f + ((size_t)(kf * 12 + nf) * 64 + lane) * 8);
            }

    f32x4 ldv[2], ld2v[2];
#pragma unroll
    for (int uf = 0; uf < 2; ++uf) {
        ldv[uf] = *(const f32x4*)(ldg + b * V + 32 * uq + 16 * uf + lg * 4);
        ld2v[uf] = 2.0f * ldv[uf] * ldv[uf];
    }

    // stage_x: wave stages rows [16w,16w+16) fp32; LDS dest linear, 16B-slot swizzle on SOURCE:
    // slot16 ^= ((row&3)<<1) | ((row>>3)&1)  -> even 8-way slot-class spread, conflict-free b128.
    auto stage_x = [&](int tt, int buf) {
        const char* src = (const char*)(xb + (size_t)tt * (V * F));
        char* dst = (char*)&xbuf[buf][0] + w * 4096;
#pragma unroll
        for (int j = 0; j < 4; ++j) {
            int n = j * 64 + lane;               // 0..255 chunks of 16B
            int rloc = n >> 4, slot = n & 15;
            int e = ((rloc & 3) << 1) | ((rloc >> 3) & 1);
            int row = 16 * w + rloc;
            const char* g = src + row * 256 + ((slot ^ e) << 4);
            __builtin_amdgcn_global_load_lds(
                (const __attribute__((address_space(1))) void*)g,
                (__attribute__((address_space(3))) void*)(dst + n * 16), 16, 0, 0);
        }
    };

    // ---- prologue ----
    stage_x(0, 0);
    asm volatile("s_waitcnt vmcnt(0)" ::: "memory");
    __builtin_amdgcn_sched_barrier(0);
    __builtin_amdgcn_s_barrier();
    __builtin_amdgcn_sched_barrier(0);

    const int eL = ((lr & 3) << 1) | ((lr >> 3) & 1);   // swizzle key (row%16 == lr patterns)

    for (int tt = 0; tt < TPB; ++tt) {
        const int cur = tt & 1;

        // ---- issue x(tt+1); counted wait keeps them in flight all iteration ----
        if (tt + 1 < TPB) {
            stage_x(tt + 1, cur ^ 1);
            asm volatile("s_waitcnt vmcnt(4)" ::: "memory");
        } else {
            asm volatile("s_waitcnt vmcnt(0)" ::: "memory");
        }
        __builtin_amdgcn_sched_barrier(0);
        __builtin_amdgcn_s_barrier();            // barA: x(tt) ready; zc(tt-1) fully consumed
        __builtin_amdgcn_sched_barrier(0);

        // ---- xa fragments (8 x ds_read_b128, conflict-free) ----
        bf16x8 xa[2][2];
        const char* xc = (const char*)&xbuf[cur][0];
#pragma unroll
        for (int rv = 0; rv < 2; ++rv) {
            const char* rp = xc + (32 * uq + 16 * rv + lr) * 256;
#pragma unroll
            for (int kf = 0; kf < 2; ++kf) {
                const int s0 = kf * 8 + lg * 2;
                f32x4 a0 = *(const f32x4*)(rp + ((s0 ^ eL) << 4));
                f32x4 a1 = *(const f32x4*)(rp + (((s0 + 1) ^ eL) << 4));
                uint4 u;
                u.x = f2bf(a0[0]) | ((unsigned)f2bf(a0[1]) << 16);
                u.y = f2bf(a0[2]) | ((unsigned)f2bf(a0[3]) << 16);
                u.z = f2bf(a1[0]) | ((unsigned)f2bf(a1[1]) << 16);
                u.w = f2bf(a1[2]) | ((unsigned)f2bf(a1[3]) << 16);
                xa[rv][kf] = __builtin_bit_cast(bf16x8, u);
            }
        }

        // ---- GEMM1 (pure-register MFMA): Zm->acc, Z1/Z2 -> z ----
        f32x4 acc[2][2], z1[2][2], z2[2][2];
#pragma unroll
        for (int a = 0; a < 2; ++a)
#pragma unroll
            for (int o = 0; o < 2; ++o) {
                acc[a][o] = (f32x4){0.f, 0.f, 0.f, 0.f};
                z1[a][o] = (f32x4){0.f, 0.f, 0.f, 0.f};
                z2[a][o] = (f32x4){0.f, 0.f, 0.f, 0.f};
            }
#pragma unroll
        for (int kf = 0; kf < 2; ++kf)
#pragma unroll
            for (int rv = 0; rv < 2; ++rv)
#pragma unroll
                for (int i = 0; i < 2; ++i) {
                    acc[rv][i] = __builtin_amdgcn_mfma_f32_16x16x32_bf16(xa[rv][kf], th_r[0][i][kf], acc[rv][i], 0, 0, 0);
                    z1[rv][i] = __builtin_amdgcn_mfma_f32_16x16x32_bf16(xa[rv][kf], th_r[1][i][kf], z1[rv][i], 0, 0, 0);
                    z2[rv][i] = __builtin_amdgcn_mfma_f32_16x16x32_bf16(xa[rv][kf], th_r[2][i][kf], z2[rv][i], 0, 0, 0);
                }

        // ---- fp32 diag (v-slab == u-slab) + pack + zc writes ([o][v], swizzled) ----
#pragma unroll
        for (int uf = 0; uf < 2; ++uf)
#pragma unroll
            for (int of = 0; of < 2; ++of) {
                acc[uf][of] += ldv[uf] * z1[uf][of] + ld2v[uf] * z2[uf][of];
                const int ro = 32 * oh + of * 16 + lr;
                const int slot = 4 * uq + 2 * uf + (lg >> 1);
                const int byte = ro * 256 + (((slot ^ eL)) << 4) + (lg & 1) * 8;
                f32x4 v1 = z1[uf][of], v2 = z2[uf][of];
                uint2 q1, q2;
                q1.x = f2bf(v1[0]) | ((unsigned)f2bf(v1[1]) << 16);
                q1.y = f2bf(v1[2]) | ((unsigned)f2bf(v1[3]) << 16);
                q2.x = f2bf(v2[0]) | ((unsigned)f2bf(v2[1]) << 16);
                q2.y = f2bf(v2[2]) | ((unsigned)f2bf(v2[3]) << 16);
                *(uint2*)((char*)zc1 + byte) = q1;
                *(uint2*)((char*)zc2 + byte) = q2;
            }

        asm volatile("s_waitcnt lgkmcnt(0)" ::: "memory");
        __builtin_amdgcn_sched_barrier(0);
        __builtin_amdgcn_s_barrier();            // barB: zc ready
        __builtin_amdgcn_sched_barrier(0);

        // ---- GEMM2: acc += Acat[u-slab][256] @ Zcat[:, o-half]; af from regs, 2 MFMA per zb ----
#pragma unroll
        for (int kk = 0; kk < 8; ++kk) {
            const char* zsrc = (kk < 4) ? (const char*)zc1 : (const char*)zc2;
            bf16x8 zb[2];
#pragma unroll
            for (int of = 0; of < 2; ++of) {
                const int ro = 32 * oh + of * 16 + lr;
                const int slot = (kk & 3) * 4 + lg;
                zb[of] = *(const bf16x8*)(zsrc + ro * 256 + ((slot ^ eL) << 4));
            }
#pragma unroll
            for (int uf = 0; uf < 2; ++uf)
#pragma unroll
                for (int of = 0; of < 2; ++of)
                    acc[uf][of] = __builtin_amdgcn_mfma_f32_16x16x32_bf16(af_r[uf][kk], zb[of], acc[uf][of], 0, 0, 0);
        }

        // ---- epilogue: relu + store out[u-slab][o-half] for t ----
        float* obt = out + ((size_t)(b * T + t0 + tt)) * (V * O);
#pragma unroll
        for (int uf = 0; uf < 2; ++uf)
#pragma unroll
            for (int of = 0; of < 2; ++of)
#pragma unroll
                for (int j = 0; j < 4; ++j) {
                    const int u = 32 * uq + 16 * uf + lg * 4 + j;
                    const int o = 32 * oh + 16 * of + lr;
                    const float r = acc[uf][of][j];
                    obt[u * 64 + o] = r > 0.f ? r : 0.f;
                }
        // no end barrier: barA(t+1) gates zc overwrite; xbuf dbuf gates itself via vmcnt(4)+barA
    }
}

}  // namespace

extern "C" void kernel_launch(void* const* d_in, const int* in_sizes, int n_in,
                              void* d_out, int out_size, void* d_ws, size_t ws_size,
                              hipStream_t stream) {
    const float* x = (const float*)d_in[0];      // (B,T,V,F)
    const float* W = (const float*)d_in[1];      // (B,V,V)
    const float* Theta = (const float*)d_in[2];  // (3,F,O)
    float* outp = (float*)d_out;                 // (B,T,V,O)

    unsigned short* acat_f = (unsigned short*)d_ws;
    unsigned short* tht_f = (unsigned short*)((char*)d_ws + WS_THT_OFF);
    float* ldg = (float*)((char*)d_ws + WS_LDG_OFF);

    prep<<<B + 1, 256, 0, stream>>>(W, Theta, acat_f, tht_f, ldg);
    graph_conv_main<<<dim3(T / TPB, B), 512, 0, stream>>>(x, acat_f, tht_f, ldg, outp);
}

// Round 14
// 79.218 us; speedup vs baseline: 1.1657x; 1.1657x over previous
//
#include <hip/hip_runtime.h>

typedef __attribute__((ext_vector_type(8))) short bf16x8;
typedef __attribute__((ext_vector_type(4))) float f32x4;

namespace {

constexpr int B = 32, T = 128, V = 128, F = 64, O = 64;
constexpr int TPB = 16;   // t-tiles per block; grid = (8, 32) = 256 blocks = 1/CU

// ws layout (bytes):
//   [acat_f bf16: B * (8 ks * 8 r2 * 64 lane) frags * 16B = 2 MiB]   fragment-major Acat
//   [tht_f  bf16: (2 ks * 12 nf * 64 lane) frags * 16B = 24 KiB]     fragment-major ThT
//   [ldg    f32 : B*V = 16 KiB]
constexpr size_t WS_THT_OFF = (size_t)B * 64 * 64 * 8 * 2;   // 2 MiB
constexpr size_t WS_LDG_OFF = WS_THT_OFF + 1536 * 8 * 2;     // +24 KiB

__device__ inline unsigned short f2bf(float f) {
    unsigned u = __builtin_bit_cast(unsigned, f);
    u += 0x7FFFu + ((u >> 16) & 1u);
    return (unsigned short)(u >> 16);
}

// ---------------- prep: fragment-major Acat/ThT, ldiag (unchanged) ----------------
__global__ __launch_bounds__(256) void prep(const float* __restrict__ W,
                                            const float* __restrict__ Theta,
                                            unsigned short* __restrict__ acat_f,
                                            unsigned short* __restrict__ tht_f,
                                            float* __restrict__ ldg) {
    const int tid = threadIdx.x;
    if (blockIdx.x == B) {
        for (int i = 0; i < 6; ++i) {
            int fi = tid + i * 256;                 // [0,1536)
            int ks = fi / 768, rem = fi % 768;
            int nf = rem >> 6, lane = rem & 63;
            int n = nf * 16 + (lane & 15);
            int f0 = ks * 32 + (lane >> 4) * 8;
            unsigned short vals[8];
#pragma unroll
            for (int j = 0; j < 8; ++j) {
                int f = f0 + j;
                float v;
                if (n < 64)       v = Theta[f * 64 + n] - Theta[2 * 4096 + f * 64 + n];
                else if (n < 128) v = Theta[4096 + f * 64 + (n - 64)];
                else              v = Theta[2 * 4096 + f * 64 + (n - 128)];
                vals[j] = f2bf(v);
            }
            *(bf16x8*)(tht_f + (size_t)fi * 8) = *(bf16x8*)vals;
        }
        return;
    }
    const int b = blockIdx.x;
    const float* Wb = W + (size_t)b * V * V;
    __shared__ float Wl[V][V + 1];
    for (int i = 0; i < V * V / 256; ++i) {
        int idx = tid + i * 256;
        Wl[idx >> 7][idx & 127] = Wb[idx];
    }
    __syncthreads();
    if (tid < V) {
        float s = 0.f;
        for (int i = 0; i < V; ++i) s += Wl[i][tid];       // deg[u] = sum_i W[i][u]
        ldg[b * V + tid] = s - 1.0f - Wl[tid][tid];        // ldiag
    }
    unsigned short* ab_f = acat_f + (size_t)b * 32768;
    for (int i = 0; i < 16; ++i) {
        int fi = tid + i * 256;                    // [0,4096)
        int ks = fi >> 9, rem = fi & 511;
        int r2 = rem >> 6, lane = rem & 63;
        int u = r2 * 16 + (lane & 15);
        int kv0 = ks * 32 + (lane >> 4) * 8;
        unsigned short vals[8];
#pragma unroll
        for (int j = 0; j < 8; ++j) {
            int kv = kv0 + j, v = kv & 127;
            float wv = Wl[v][u];
            float val = (v == u) ? 0.f : ((kv < 128) ? -wv : 2.f * wv * wv);
            vals[j] = f2bf(val);
        }
        *(bf16x8*)(ab_f + (size_t)fi * 8) = *(bf16x8*)vals;
    }
}

// ---------------- main: all-LDS operands, depth-2 reg prefetch, coalesced stores ----------------
__global__ __launch_bounds__(512, 1) void graph_conv_main(
    const float* __restrict__ x, const unsigned short* __restrict__ acat_f,
    const unsigned short* __restrict__ tht_f, const float* __restrict__ ldg,
    float* __restrict__ out) {
    const int t0 = blockIdx.x * TPB, b = blockIdx.y;
    const int tid = threadIdx.x;                 // 0..511
    const int lane = tid & 63, w = tid >> 6;
    const int uq = w & 3;                        // u/v-slab [32uq, 32uq+32)
    const int oh = w >> 2;                       // o-half  [32oh, 32oh+32)
    const int lr = lane & 15, lg = lane >> 4;

    __shared__ __align__(16) unsigned short tht_s[12288];    // 24 KB
    __shared__ __align__(16) unsigned short acat_s[32768];   // 64 KB
    __shared__ __align__(16) unsigned short xbuf[2][8192];   // 32 KB bf16, XOR-swizzled
    __shared__ __align__(16) unsigned short zc[16384];       // 32 KB: zc1|zc2, reused as out-stage
    // total 152 KB -> 1 block/CU

    const float* xb = x + ((size_t)(b * T + t0)) * (V * F);

    // ---- ldiag fragments (global scalar loads, prologue-only) ----
    f32x4 ldv[2], ld2v[2];
#pragma unroll
    for (int uf = 0; uf < 2; ++uf) {
        ldv[uf] = *(const f32x4*)(ldg + b * V + 32 * uq + 16 * uf + lg * 4);
        ld2v[uf] = 2.0f * ldv[uf] * ldv[uf];
    }

    // ---- stage acat_s + tht_s via global_load_lds (linear both sides) ----
    {
        const unsigned short* ag = acat_f + (size_t)b * 32768;
#pragma unroll
        for (int i = 0; i < 8; ++i) {
            int c = tid + i * 512;               // 4096 chunks of 16B
            __builtin_amdgcn_global_load_lds(
                (const __attribute__((address_space(1))) void*)(ag + c * 8),
                (__attribute__((address_space(3))) void*)(acat_s + c * 8), 16, 0, 0);
        }
#pragma unroll
        for (int i = 0; i < 3; ++i) {
            int c = tid + i * 512;               // 1536 chunks
            __builtin_amdgcn_global_load_lds(
                (const __attribute__((address_space(1))) void*)(tht_f + c * 8),
                (__attribute__((address_space(3))) void*)(tht_s + c * 8), 16, 0, 0);
        }
    }

    // pf helpers: per thread 4 float4 (64 B) of one x tile
    auto load_pf = [&](int tt, float4 (&pf)[4]) {
        const float4* src = (const float4*)(xb + (size_t)tt * (V * F));
#pragma unroll
        for (int i = 0; i < 4; ++i) pf[i] = src[tid + i * 512];
    };
    // store_pf: fp32 -> bf16, 8B chunks, slot16 ^= (row&7) swizzle
    auto store_pf = [&](int buf, float4 (&pf)[4]) {
#pragma unroll
        for (int i = 0; i < 4; ++i) {
            int p = tid + i * 512;               // float4-chunk idx in 128x64 tile
            int row = p >> 4, c4 = p & 15;
            uint2 q;
            q.x = f2bf(pf[i].x) | ((unsigned)f2bf(pf[i].y) << 16);
            q.y = f2bf(pf[i].z) | ((unsigned)f2bf(pf[i].w) << 16);
            *(uint2*)((char*)xbuf[buf] +
                      row * 128 + (((c4 >> 1) ^ (row & 7)) << 4) + (c4 & 1) * 8) = q;
        }
    };

    // ---- prologue: FIXED (r13 bug #2) — single full drain, no issue-order assumption ----
    float4 pfA[4], pfB[4];
    load_pf(0, pfA);
    load_pf(1, pfB);
    asm volatile("s_waitcnt vmcnt(0)" ::: "memory");   // drain gl_lds + pfA + pfB (prologue-only cost)
    __builtin_amdgcn_sched_barrier(0);
    store_pf(0, pfA);
    asm volatile("s_waitcnt lgkmcnt(0)" ::: "memory");
    __builtin_amdgcn_sched_barrier(0);
    __builtin_amdgcn_s_barrier();
    __builtin_amdgcn_sched_barrier(0);

    // ---- one t-iteration ----
    auto iter = [&](int tt, float4 (&pfRdy)[4], float4 (&pfNew)[4]) {
        const int cur = tt & 1;
        if (tt + 2 < TPB) load_pf(tt + 2, pfNew);     // in flight across the whole iteration

        // ---- xa fragments (4 x ds_read_b128 from bf16 xbuf, conflict-free) ----
        bf16x8 xa[2][2];
#pragma unroll
        for (int rv = 0; rv < 2; ++rv) {
            const int row = 32 * uq + 16 * rv + lr;
            const char* rp = (const char*)xbuf[cur] + row * 128;
            const int rs = row & 7;
#pragma unroll
            for (int kf = 0; kf < 2; ++kf)
                xa[rv][kf] = *(const bf16x8*)(rp + (((kf * 4 + lg) ^ rs) << 4));
        }

        // ---- GEMM1: Zm -> acc, Z1/Z2 -> z; tb from tht_s ----
        f32x4 acc[2][2], z1[2][2], z2[2][2];
#pragma unroll
        for (int a = 0; a < 2; ++a)
#pragma unroll
            for (int o = 0; o < 2; ++o) {
                acc[a][o] = (f32x4){0.f, 0.f, 0.f, 0.f};
                z1[a][o] = (f32x4){0.f, 0.f, 0.f, 0.f};
                z2[a][o] = (f32x4){0.f, 0.f, 0.f, 0.f};
            }
#pragma unroll
        for (int kf = 0; kf < 2; ++kf)
#pragma unroll
            for (int i = 0; i < 2; ++i) {
                bf16x8 t0b = *(const bf16x8*)(tht_s + ((kf * 12 + 0 + 2 * oh + i) * 64 + lane) * 8);
                bf16x8 t1b = *(const bf16x8*)(tht_s + ((kf * 12 + 4 + 2 * oh + i) * 64 + lane) * 8);
                bf16x8 t2b = *(const bf16x8*)(tht_s + ((kf * 12 + 8 + 2 * oh + i) * 64 + lane) * 8);
#pragma unroll
                for (int rv = 0; rv < 2; ++rv) {
                    acc[rv][i] = __builtin_amdgcn_mfma_f32_16x16x32_bf16(xa[rv][kf], t0b, acc[rv][i], 0, 0, 0);
                    z1[rv][i] = __builtin_amdgcn_mfma_f32_16x16x32_bf16(xa[rv][kf], t1b, z1[rv][i], 0, 0, 0);
                    z2[rv][i] = __builtin_amdgcn_mfma_f32_16x16x32_bf16(xa[rv][kf], t2b, z2[rv][i], 0, 0, 0);
                }
            }

        // ---- fp32 diag (v-slab == u-slab) + pack + zc writes ([o=64][v=128], slot^=lr) ----
        char* zc1p = (char*)zc;
        char* zc2p = (char*)zc + 16384;
#pragma unroll
        for (int uf = 0; uf < 2; ++uf)
#pragma unroll
            for (int of = 0; of < 2; ++of) {
                acc[uf][of] += ldv[uf] * z1[uf][of] + ld2v[uf] * z2[uf][of];
                const int ro = 32 * oh + of * 16 + lr;
                const int slot = 4 * uq + 2 * uf + (lg >> 1);
                const int byte = ro * 256 + (((slot ^ lr)) << 4) + (lg & 1) * 8;
                f32x4 v1 = z1[uf][of], v2 = z2[uf][of];
                uint2 q1, q2;
                q1.x = f2bf(v1[0]) | ((unsigned)f2bf(v1[1]) << 16);
                q1.y = f2bf(v1[2]) | ((unsigned)f2bf(v1[3]) << 16);
                q2.x = f2bf(v2[0]) | ((unsigned)f2bf(v2[1]) << 16);
                q2.y = f2bf(v2[2]) | ((unsigned)f2bf(v2[3]) << 16);
                *(uint2*)(zc1p + byte) = q1;
                *(uint2*)(zc2p + byte) = q2;
            }

        asm volatile("s_waitcnt lgkmcnt(0)" ::: "memory");
        __builtin_amdgcn_sched_barrier(0);
        __builtin_amdgcn_s_barrier();                 // barB: zc ready
        __builtin_amdgcn_sched_barrier(0);

        // ---- GEMM2: af from acat_s, zb from zc ----
#pragma unroll
        for (int kk = 0; kk < 8; ++kk) {
            const char* zsrc = (kk < 4) ? zc1p : zc2p;
            bf16x8 af[2];
#pragma unroll
            for (int uf = 0; uf < 2; ++uf)
                af[uf] = *(const bf16x8*)(acat_s + ((kk * 8 + 2 * uq + uf) * 64 + lane) * 8);
            bf16x8 zb[2];
#pragma unroll
            for (int of = 0; of < 2; ++of) {
                const int ro = 32 * oh + of * 16 + lr;
                const int slot = (kk & 3) * 4 + lg;
                zb[of] = *(const bf16x8*)(zsrc + ro * 256 + ((slot ^ lr) << 4));
            }
#pragma unroll
            for (int uf = 0; uf < 2; ++uf)
#pragma unroll
                for (int of = 0; of < 2; ++of)
                    acc[uf][of] = __builtin_amdgcn_mfma_f32_16x16x32_bf16(af[uf], zb[of], acc[uf][of], 0, 0, 0);
        }

        // ---- consume pfRdy -> xbuf[cur^1]; counted vmcnt keeps pfNew in flight ----
        if (tt + 1 < TPB) {
            if (tt + 2 < TPB) {
                asm volatile("s_waitcnt vmcnt(4)" ::: "memory");
            } else {
                asm volatile("s_waitcnt vmcnt(0)" ::: "memory");
            }
            __builtin_amdgcn_sched_barrier(0);
            store_pf(cur ^ 1, pfRdy);
        }

        // ---- barD (FIX for r13 bug #1): all waves' GEMM2 zc reads done before out-stage overwrite ----
        asm volatile("s_waitcnt lgkmcnt(0)" ::: "memory");
        __builtin_amdgcn_sched_barrier(0);
        __builtin_amdgcn_s_barrier();
        __builtin_amdgcn_sched_barrier(0);

        // ---- epilogue A: relu'd acc -> LDS (reuse zc region as fp32 out-stage) ----
        float* os = (float*)zc;
#pragma unroll
        for (int uf = 0; uf < 2; ++uf)
#pragma unroll
            for (int of = 0; of < 2; ++of)
#pragma unroll
                for (int j = 0; j < 4; ++j) {
                    const int u = 32 * uq + 16 * uf + lg * 4 + j;
                    const int o = 32 * oh + 16 * of + lr;
                    const float r = acc[uf][of][j];
                    os[u * 64 + o] = r > 0.f ? r : 0.f;
                }

        asm volatile("s_waitcnt lgkmcnt(0)" ::: "memory");
        __builtin_amdgcn_sched_barrier(0);
        __builtin_amdgcn_s_barrier();                 // barC: out-stage ready (also covers xbuf write)
        __builtin_amdgcn_sched_barrier(0);

        // ---- epilogue B: coalesced dwordx4 stores ----
        {
            float* obt = out + ((size_t)(b * T + t0 + tt)) * (V * O);
            const float4* osv = (const float4*)zc;
#pragma unroll
            for (int i = 0; i < 4; ++i) {
                const int idx = tid + i * 512;
                *(float4*)(obt + idx * 4) = osv[idx];
            }
        }

        // barA for next iter: out-stage reads done -> zc free; xbuf[cur^1] complete
        asm volatile("s_waitcnt lgkmcnt(0)" ::: "memory");
        __builtin_amdgcn_sched_barrier(0);
        __builtin_amdgcn_s_barrier();
        __builtin_amdgcn_sched_barrier(0);
    };

    for (int tt = 0; tt < TPB; tt += 2) {
        iter(tt, pfB, pfA);       // even: pfB holds tile tt+1, pfA refilled with tile tt+2
        iter(tt + 1, pfA, pfB);   // odd:  pfA holds tile tt+2, pfB refilled with tile tt+3
    }
}

}  // namespace

extern "C" void kernel_launch(void* const* d_in, const int* in_sizes, int n_in,
                              void* d_out, int out_size, void* d_ws, size_t ws_size,
                              hipStream_t stream) {
    const float* x = (const float*)d_in[0];      // (B,T,V,F)
    const float* W = (const float*)d_in[1];      // (B,V,V)
    const float* Theta = (const float*)d_in[2];  // (3,F,O)
    float* outp = (float*)d_out;                 // (B,T,V,O)

    unsigned short* acat_f = (unsigned short*)d_ws;
    unsigned short* tht_f = (unsigned short*)((char*)d_ws + WS_THT_OFF);
    float* ldg = (float*)((char*)d_ws + WS_LDG_OFF);

    prep<<<B + 1, 256, 0, stream>>>(W, Theta, acat_f, tht_f, ldg);
    graph_conv_main<<<dim3(T / TPB, B), 512, 0, stream>>>(x, acat_f, tht_f, ldg, outp);
}